// Round 1
// baseline (127.866 us; speedup 1.0000x reference)
//
#include <hip/hip_runtime.h>
#include <hip/hip_bf16.h>
#include <stdint.h>

// Problem constants
#define Q_N   4096
#define D_N   32768
#define DIM   128
#define VOCAB 32000

#define NCHUNK 16                    // doc chunks (grid.y)
#define CHUNK  (D_N / NCHUNK)        // 2048 docs per chunk
#define QTILE  128                   // queries per block
#define DSUB   128                   // docs per LDS subtile
#define NSLOT  (NCHUNK * 2)          // partial slots: chunk x wm-strip

typedef short  short8 __attribute__((ext_vector_type(8)));
typedef float  f32x4  __attribute__((ext_vector_type(4)));

// Workspace layout (bytes)
#define WS_QBF  0u                               // 4096*128*2   = 1 MiB
#define WS_DBF  0x100000u                        // 32768*128*2  = 8 MiB
#define WS_PMAX 0x900000u                        // 32*4096*4    = 512 KiB
#define WS_PIDX 0x980000u                        // 32*4096*4    = 512 KiB
#define WS_SUMS 0xA00000u                        // 3 floats

// ---------------- Kernel A: fp32 -> bf16 convert (+ zero sums) ----------------
__device__ inline ushort f2bf(float f) {
  uint32_t u = __float_as_uint(f);
  u += 0x7FFFu + ((u >> 16) & 1u);   // RNE
  return (ushort)(u >> 16);
}

__global__ void convert_kernel(const float* __restrict__ qe, const float* __restrict__ de,
                               ushort* __restrict__ qb, ushort* __restrict__ db,
                               float* __restrict__ sums) {
  int i = blockIdx.x * 256 + threadIdx.x;
  if (i < 3) sums[i] = 0.0f;         // ws is re-poisoned every launch
  const int NQ4 = Q_N * DIM / 4;     // 131072 float4s
  float4 v;
  ushort* dst;
  if (i < NQ4) {
    v = ((const float4*)qe)[i];
    dst = qb + (size_t)i * 4;
  } else {
    int j = i - NQ4;                 // < 1048576 (grid sized exactly)
    v = ((const float4*)de)[j];
    dst = db + (size_t)j * 4;
  }
  ushort4 o;
  o.x = f2bf(v.x); o.y = f2bf(v.y); o.z = f2bf(v.z); o.w = f2bf(v.w);
  *(ushort4*)dst = o;
}

// ---------------- Kernel B: MaxSim partial (GEMM + row-max/argmax epilogue) ----------------
// Computes S^T tiles: M = docs (rows), N = queries (cols), K = 128.
// A = doc bf16 [D][128], B = query bf16 [Q][128], both [out][K] row-major (B^T GEMM idiom).
// mfma_f32_16x16x32_bf16 layouts (m89-verified):
//   A[m][k]: m = lane&15, k = (lane>>4)*8 + e
//   B[k][n]: n = lane&15, k = (lane>>4)*8 + e
//   C[r]:    col = lane&15, row = (lane>>4)*4 + r
__global__ __launch_bounds__(256, 2)
void maxsim_kernel(const ushort* __restrict__ dbf, const ushort* __restrict__ qbf,
                   float* __restrict__ pmax, int* __restrict__ pidx) {
  __shared__ ushort lds[2][DSUB * DIM];   // 2 x 32 KiB, double-buffered doc tile

  const int tid  = threadIdx.x;
  const int lane = tid & 63;
  const int wid  = tid >> 6;
  const int wm   = wid >> 1;              // doc strip: rows [wm*64, wm*64+64)
  const int wn   = wid & 1;               // query strip: cols [wn*64, wn*64+64)
  const int qblock = blockIdx.x * QTILE;
  const int chunk0 = blockIdx.y * CHUNK;

  // ---- B fragments (queries) loaded once from global, held in registers ----
  short8 bfr[4][4];                       // [nf][kk]
  #pragma unroll
  for (int nf = 0; nf < 4; ++nf) {
    int qrow = qblock + wn * 64 + nf * 16 + (lane & 15);
    const ushort* p = qbf + (size_t)qrow * DIM + ((lane >> 4) * 8);
    #pragma unroll
    for (int kk = 0; kk < 4; ++kk)
      bfr[nf][kk] = *(const short8*)(p + kk * 32);
  }

  float rmax[4]; int ridx[4];
  #pragma unroll
  for (int nf = 0; nf < 4; ++nf) { rmax[nf] = -3.0e38f; ridx[nf] = 0; }

  const char* gdoc = (const char*)(dbf + (size_t)chunk0 * DIM);

  // Stage doc subtile `st` into LDS buffer `b`.
  // LDS dest is linear (global_load_lds writes base+lane*16); the st_? XOR swizzle
  // (byte ^= ((row&7)<<4)) is applied to the GLOBAL source, and again on ds_read.
  auto stage = [&](int b, int st) {
    const char* gt = gdoc + st * (DSUB * DIM * 2);
    char* lb = (char*)&lds[b][0] + wid * 8192;
    #pragma unroll
    for (int it = 0; it < 8; ++it) {
      int off = wid * 8192 + it * 1024 + lane * 16;
      int swz = off ^ (((off >> 8) & 7) << 4);
      __builtin_amdgcn_global_load_lds(
          (const __attribute__((address_space(1))) uint32_t*)(gt + swz),
          (__attribute__((address_space(3))) uint32_t*)(lb + it * 1024),
          16, 0, 0);
    }
  };

  stage(0, 0);
  __syncthreads();   // compiler emits vmcnt(0) drain before barrier

  #pragma unroll 1
  for (int st = 0; st < CHUNK / DSUB; ++st) {   // 16 subtiles
    const int b = st & 1;
    if (st + 1 < CHUNK / DSUB) stage(b ^ 1, st + 1);

    const char* lb = (const char*)&lds[b][0];
    #pragma unroll
    for (int mf = 0; mf < 4; ++mf) {
      short8 afr[4];
      int arow = wm * 64 + mf * 16 + (lane & 15);
      #pragma unroll
      for (int kk = 0; kk < 4; ++kk) {
        int abyte = (arow * 256 + kk * 64 + ((lane >> 4) * 16)) ^ ((arow & 7) << 4);
        afr[kk] = *(const short8*)(lb + abyte);
      }
      #pragma unroll
      for (int nf = 0; nf < 4; ++nf) {
        f32x4 acc = {0.f, 0.f, 0.f, 0.f};
        #pragma unroll
        for (int kk = 0; kk < 4; ++kk)
          acc = __builtin_amdgcn_mfma_f32_16x16x32_bf16(afr[kk], bfr[nf][kk], acc, 0, 0, 0);
        // running max/argmax; code is wave-uniform (SGPR) + compile-time const
        const int code0 = st * 128 + wm * 64 + mf * 16;
        #pragma unroll
        for (int r = 0; r < 4; ++r) {
          float v = acc[r];
          bool gt = v > rmax[nf];
          rmax[nf] = gt ? v : rmax[nf];
          ridx[nf] = gt ? (code0 + r) : ridx[nf];
        }
      }
    }
    __syncthreads();
  }

  // ---- cross-lane reduce (lanes l, l^16, l^32, l^48 share a query column) ----
  const int slot = blockIdx.y * 2 + wm;
  #pragma unroll
  for (int nf = 0; nf < 4; ++nf) {
    float m = rmax[nf];
    int gi = chunk0 + ridx[nf] + ((lane >> 4) << 2);   // full doc id
    #pragma unroll
    for (int s = 16; s <= 32; s <<= 1) {
      float om = __shfl_xor(m, s);
      int   oi = __shfl_xor(gi, s);
      if (om > m || (om == m && oi < gi)) { m = om; gi = oi; }
    }
    if (lane < 16) {
      int q = qblock + wn * 64 + nf * 16 + lane;
      pmax[slot * Q_N + q] = m;
      pidx[slot * Q_N + q] = gi;
    }
  }
}

// ---------------- Kernel C1: reduce partials per query, gather weights, partial sums ----------------
__global__ void reduce_kernel(const float* __restrict__ pmax, const int* __restrict__ pidx,
                              const int* __restrict__ qtok, const int* __restrict__ dtok,
                              const float* __restrict__ qwt, const float* __restrict__ dwt,
                              float* __restrict__ sums) {
  int q = blockIdx.x * 256 + threadIdx.x;
  float m = -3.0e38f; int best = 0;
  #pragma unroll 4
  for (int s = 0; s < NSLOT; ++s) {
    float v = pmax[s * Q_N + q];
    int   i = pidx[s * Q_N + q];
    if (v > m || (v == m && i < best)) { m = v; best = i; }
  }
  float c  = qwt[qtok[q]] * dwt[dtok[best]];
  float s0 = c, s1 = m * c, s2 = m;
  #pragma unroll
  for (int sh = 32; sh >= 1; sh >>= 1) {
    s0 += __shfl_down(s0, sh);
    s1 += __shfl_down(s1, sh);
    s2 += __shfl_down(s2, sh);
  }
  __shared__ float red[3][4];
  int lane = threadIdx.x & 63, w = threadIdx.x >> 6;
  if (lane == 0) { red[0][w] = s0; red[1][w] = s1; red[2][w] = s2; }
  __syncthreads();
  if (threadIdx.x == 0) {
    atomicAdd(&sums[0], red[0][0] + red[0][1] + red[0][2] + red[0][3]);
    atomicAdd(&sums[1], red[1][0] + red[1][1] + red[1][2] + red[1][3]);
    atomicAdd(&sums[2], red[2][0] + red[2][1] + red[2][2] + red[2][3]);
  }
}

// ---------------- Kernel C2: finalize ----------------
__global__ void finalize_kernel(const float* __restrict__ sums, float* __restrict__ out) {
  float s0 = sums[0], s1 = sums[1], s2 = sums[2];
  out[0] = (s0 > 0.0f) ? (s1 / s0) : (s2 / (float)Q_N);  // zero-sum fallback = uniform weights
}

// ---------------- Launch ----------------
extern "C" void kernel_launch(void* const* d_in, const int* in_sizes, int n_in,
                              void* d_out, int out_size, void* d_ws, size_t ws_size,
                              hipStream_t stream) {
  const float* qe   = (const float*)d_in[0];
  const float* de   = (const float*)d_in[1];
  const int*   qtok = (const int*)d_in[2];
  const int*   dtok = (const int*)d_in[3];
  const float* qwt  = (const float*)d_in[4];
  const float* dwt  = (const float*)d_in[5];
  float* out = (float*)d_out;

  char* ws = (char*)d_ws;
  ushort* qbf  = (ushort*)(ws + WS_QBF);
  ushort* dbf  = (ushort*)(ws + WS_DBF);
  float*  pmax = (float*)(ws + WS_PMAX);
  int*    pidx = (int*)(ws + WS_PIDX);
  float*  sums = (float*)(ws + WS_SUMS);

  const int NQ4 = Q_N * DIM / 4, ND4 = D_N * DIM / 4;
  convert_kernel<<<(NQ4 + ND4) / 256, 256, 0, stream>>>(qe, de, qbf, dbf, sums);

  dim3 g(Q_N / QTILE, NCHUNK);
  maxsim_kernel<<<g, 256, 0, stream>>>(dbf, qbf, pmax, pidx);

  reduce_kernel<<<Q_N / 256, 256, 0, stream>>>(pmax, pidx, qtok, dtok, qwt, dwt, sums);
  finalize_kernel<<<1, 1, 0, stream>>>(sums, out);
}

// Round 2
// 126.962 us; speedup vs baseline: 1.0071x; 1.0071x over previous
//
#include <hip/hip_runtime.h>
#include <hip/hip_bf16.h>
#include <stdint.h>

// Problem constants
#define Q_N   4096
#define D_N   32768
#define DIM   128
#define VOCAB 32000

#define NCHUNK 16                    // doc chunks (grid.y)
#define CHUNK  (D_N / NCHUNK)        // 2048 docs per chunk
#define QTILE  128                   // queries per block
#define DSUB   128                   // docs per LDS subtile
#define NSLOT  (NCHUNK * 2)          // partial slots: chunk x wm-strip

typedef short  short8 __attribute__((ext_vector_type(8)));
typedef float  f32x4  __attribute__((ext_vector_type(4)));

// Workspace layout (bytes)
#define WS_QBF  0u                               // 4096*128*2   = 1 MiB
#define WS_DBF  0x100000u                        // 32768*128*2  = 8 MiB
#define WS_PMAX 0x900000u                        // 32*4096*4    = 512 KiB
#define WS_PIDX 0x980000u                        // 32*4096*4    = 512 KiB
#define WS_SUMS 0xA00000u                        // 3 floats

// ---------------- Kernel A: fp32 -> bf16 convert (+ zero sums) ----------------
__device__ inline ushort f2bf(float f) {
  uint32_t u = __float_as_uint(f);
  u += 0x7FFFu + ((u >> 16) & 1u);   // RNE
  return (ushort)(u >> 16);
}

__global__ void convert_kernel(const float* __restrict__ qe, const float* __restrict__ de,
                               ushort* __restrict__ qb, ushort* __restrict__ db,
                               float* __restrict__ sums) {
  int i = blockIdx.x * 256 + threadIdx.x;
  if (i < 3) sums[i] = 0.0f;         // ws is re-poisoned every launch
  const int NQ4 = Q_N * DIM / 4;     // 131072 float4s
  float4 v;
  ushort* dst;
  if (i < NQ4) {
    v = ((const float4*)qe)[i];
    dst = qb + (size_t)i * 4;
  } else {
    int j = i - NQ4;                 // < 1048576 (grid sized exactly)
    v = ((const float4*)de)[j];
    dst = db + (size_t)j * 4;
  }
  ushort4 o;
  o.x = f2bf(v.x); o.y = f2bf(v.y); o.z = f2bf(v.z); o.w = f2bf(v.w);
  *(ushort4*)dst = o;
}

// ---------------- Kernel B: MaxSim partial (GEMM + row-max/argmax epilogue) ----------------
// Computes S^T tiles: M = docs (rows), N = queries (cols), K = 128.
// 512 threads = 8 waves, wave grid 2M x 4N over a 128-doc x 128-query tile:
//   wm = wid>>2 (doc strip of 64 rows), wn = wid&3 (query strip of 32 cols).
// Per wave: mf in [0,4) 16-row A-frags, nf in [0,2) 16-col B-frags.
// mfma_f32_16x16x32_bf16 layouts (m89-verified):
//   A[m][k]: m = lane&15, k = (lane>>4)*8 + e
//   B[k][n]: n = lane&15, k = (lane>>4)*8 + e
//   C[r]:    col = lane&15, row = (lane>>4)*4 + r
__global__ __launch_bounds__(512, 4)
void maxsim_kernel(const ushort* __restrict__ dbf, const ushort* __restrict__ qbf,
                   float* __restrict__ pmax, int* __restrict__ pidx) {
  __shared__ ushort lds[2][DSUB * DIM];   // 2 x 32 KiB, double-buffered doc tile

  const int tid  = threadIdx.x;
  const int lane = tid & 63;
  const int wid  = tid >> 6;
  const int wm   = wid >> 2;              // doc strip: rows [wm*64, wm*64+64)
  const int wn   = wid & 3;               // query strip: cols [wn*32, wn*32+32)
  const int qblock = blockIdx.x * QTILE;
  const int chunk0 = blockIdx.y * CHUNK;

  // ---- B fragments (queries) loaded once from global, held in registers ----
  short8 bfr[2][4];                       // [nf][kk] = 32 VGPRs
  #pragma unroll
  for (int nf = 0; nf < 2; ++nf) {
    int qrow = qblock + wn * 32 + nf * 16 + (lane & 15);
    const ushort* p = qbf + (size_t)qrow * DIM + ((lane >> 4) * 8);
    #pragma unroll
    for (int kk = 0; kk < 4; ++kk)
      bfr[nf][kk] = *(const short8*)(p + kk * 32);
  }

  float rmax[2]; int ridx[2];
  #pragma unroll
  for (int nf = 0; nf < 2; ++nf) { rmax[nf] = -3.0e38f; ridx[nf] = 0; }

  const char* gdoc = (const char*)(dbf + (size_t)chunk0 * DIM);

  // Stage doc subtile `st` into LDS buffer `b` (8 waves x 4 KB each).
  // LDS dest is linear (global_load_lds writes base+lane*16); the XOR swizzle
  // (byte ^= ((row&7)<<4)) is applied to the GLOBAL source, and again on ds_read.
  auto stage = [&](int b, int st) {
    const char* gt = gdoc + st * (DSUB * DIM * 2);
    char* lb = (char*)&lds[b][0];
    #pragma unroll
    for (int it = 0; it < 4; ++it) {
      int off = wid * 4096 + it * 1024 + lane * 16;
      int swz = off ^ (((off >> 8) & 7) << 4);
      __builtin_amdgcn_global_load_lds(
          (const __attribute__((address_space(1))) uint32_t*)(gt + swz),
          (__attribute__((address_space(3))) uint32_t*)(lb + wid * 4096 + it * 1024),
          16, 0, 0);
    }
  };

  stage(0, 0);
  __syncthreads();

  #pragma unroll 1
  for (int st = 0; st < CHUNK / DSUB; ++st) {   // 16 subtiles
    const int b = st & 1;
    if (st + 1 < CHUNK / DSUB) stage(b ^ 1, st + 1);

    const char* lb = (const char*)&lds[b][0];
    #pragma unroll
    for (int mf = 0; mf < 4; ++mf) {
      short8 afr[4];
      int arow = wm * 64 + mf * 16 + (lane & 15);
      #pragma unroll
      for (int kk = 0; kk < 4; ++kk) {
        int abyte = (arow * 256 + kk * 64 + ((lane >> 4) * 16)) ^ ((arow & 7) << 4);
        afr[kk] = *(const short8*)(lb + abyte);
      }
      // kk outer / nf inner: 2 independent MFMAs between chain links
      f32x4 acc[2] = {{0.f,0.f,0.f,0.f},{0.f,0.f,0.f,0.f}};
      #pragma unroll
      for (int kk = 0; kk < 4; ++kk)
        #pragma unroll
        for (int nf = 0; nf < 2; ++nf)
          acc[nf] = __builtin_amdgcn_mfma_f32_16x16x32_bf16(afr[kk], bfr[nf][kk], acc[nf], 0, 0, 0);
      const int code0 = st * 128 + wm * 64 + mf * 16;
      #pragma unroll
      for (int nf = 0; nf < 2; ++nf)
        #pragma unroll
        for (int r = 0; r < 4; ++r) {
          float v = acc[nf][r];
          bool gtv = v > rmax[nf];
          rmax[nf] = gtv ? v : rmax[nf];
          ridx[nf] = gtv ? (code0 + r) : ridx[nf];
        }
    }
    __syncthreads();
  }

  // ---- cross-lane reduce (lanes l, l^16, l^32, l^48 share a query column) ----
  const int slot = blockIdx.y * 2 + wm;
  #pragma unroll
  for (int nf = 0; nf < 2; ++nf) {
    float m = rmax[nf];
    int gi = chunk0 + ridx[nf] + ((lane >> 4) << 2);   // full doc id
    #pragma unroll
    for (int s = 16; s <= 32; s <<= 1) {
      float om = __shfl_xor(m, s);
      int   oi = __shfl_xor(gi, s);
      if (om > m || (om == m && oi < gi)) { m = om; gi = oi; }
    }
    if (lane < 16) {
      int q = qblock + wn * 32 + nf * 16 + lane;
      pmax[slot * Q_N + q] = m;
      pidx[slot * Q_N + q] = gi;
    }
  }
}

// ---------------- Kernel C1: reduce partials per query, gather weights, partial sums ----------------
__global__ void reduce_kernel(const float* __restrict__ pmax, const int* __restrict__ pidx,
                              const int* __restrict__ qtok, const int* __restrict__ dtok,
                              const float* __restrict__ qwt, const float* __restrict__ dwt,
                              float* __restrict__ sums) {
  int q = blockIdx.x * 256 + threadIdx.x;
  float m = -3.0e38f; int best = 0;
  #pragma unroll 4
  for (int s = 0; s < NSLOT; ++s) {
    float v = pmax[s * Q_N + q];
    int   i = pidx[s * Q_N + q];
    if (v > m || (v == m && i < best)) { m = v; best = i; }
  }
  float c  = qwt[qtok[q]] * dwt[dtok[best]];
  float s0 = c, s1 = m * c, s2 = m;
  #pragma unroll
  for (int sh = 32; sh >= 1; sh >>= 1) {
    s0 += __shfl_down(s0, sh);
    s1 += __shfl_down(s1, sh);
    s2 += __shfl_down(s2, sh);
  }
  __shared__ float red[3][4];
  int lane = threadIdx.x & 63, w = threadIdx.x >> 6;
  if (lane == 0) { red[0][w] = s0; red[1][w] = s1; red[2][w] = s2; }
  __syncthreads();
  if (threadIdx.x == 0) {
    atomicAdd(&sums[0], red[0][0] + red[0][1] + red[0][2] + red[0][3]);
    atomicAdd(&sums[1], red[1][0] + red[1][1] + red[1][2] + red[1][3]);
    atomicAdd(&sums[2], red[2][0] + red[2][1] + red[2][2] + red[2][3]);
  }
}

// ---------------- Kernel C2: finalize ----------------
__global__ void finalize_kernel(const float* __restrict__ sums, float* __restrict__ out) {
  float s0 = sums[0], s1 = sums[1], s2 = sums[2];
  out[0] = (s0 > 0.0f) ? (s1 / s0) : (s2 / (float)Q_N);  // zero-sum fallback = uniform weights
}

// ---------------- Launch ----------------
extern "C" void kernel_launch(void* const* d_in, const int* in_sizes, int n_in,
                              void* d_out, int out_size, void* d_ws, size_t ws_size,
                              hipStream_t stream) {
  const float* qe   = (const float*)d_in[0];
  const float* de   = (const float*)d_in[1];
  const int*   qtok = (const int*)d_in[2];
  const int*   dtok = (const int*)d_in[3];
  const float* qwt  = (const float*)d_in[4];
  const float* dwt  = (const float*)d_in[5];
  float* out = (float*)d_out;

  char* ws = (char*)d_ws;
  ushort* qbf  = (ushort*)(ws + WS_QBF);
  ushort* dbf  = (ushort*)(ws + WS_DBF);
  float*  pmax = (float*)(ws + WS_PMAX);
  int*    pidx = (int*)(ws + WS_PIDX);
  float*  sums = (float*)(ws + WS_SUMS);

  const int NQ4 = Q_N * DIM / 4, ND4 = D_N * DIM / 4;
  convert_kernel<<<(NQ4 + ND4) / 256, 256, 0, stream>>>(qe, de, qbf, dbf, sums);

  dim3 g(Q_N / QTILE, NCHUNK);
  maxsim_kernel<<<g, 512, 0, stream>>>(dbf, qbf, pmax, pidx);

  reduce_kernel<<<Q_N / 256, 256, 0, stream>>>(pmax, pidx, qtok, dtok, qwt, dwt, sums);
  finalize_kernel<<<1, 1, 0, stream>>>(sums, out);
}